// Round 2
// baseline (11542.728 us; speedup 1.0000x reference)
//
#include <hip/hip_runtime.h>
#include <math.h>

#define BB 32
#define CC 256
#define HWt 1024          // H*W
#define NN 32768          // B*H*W
#define KK 2048
#define RQDEPTH 4

// ===== numpy pairwise sum-of-squares, blocksize-128 tree, bit-exact =====
// numpy: n=256 -> P(a[0:128]) + P(a[128:256]); each 128-block: 8 accumulators,
// r[j] = sum_{i=0,8,...,120} a[i+j] (sequential), combine ((r0+r1)+(r2+r3))+((r4+r5)+(r6+r7)).
__device__ __forceinline__ float pw128sq(const float4* __restrict__ a4) {
  float r[8];
  {
    float4 p = a4[0], q = a4[1];
    r[0] = __fmul_rn(p.x, p.x); r[1] = __fmul_rn(p.y, p.y);
    r[2] = __fmul_rn(p.z, p.z); r[3] = __fmul_rn(p.w, p.w);
    r[4] = __fmul_rn(q.x, q.x); r[5] = __fmul_rn(q.y, q.y);
    r[6] = __fmul_rn(q.z, q.z); r[7] = __fmul_rn(q.w, q.w);
  }
  for (int i = 1; i < 16; ++i) {
    float4 p = a4[2 * i], q = a4[2 * i + 1];
    r[0] = __fadd_rn(r[0], __fmul_rn(p.x, p.x));
    r[1] = __fadd_rn(r[1], __fmul_rn(p.y, p.y));
    r[2] = __fadd_rn(r[2], __fmul_rn(p.z, p.z));
    r[3] = __fadd_rn(r[3], __fmul_rn(p.w, p.w));
    r[4] = __fadd_rn(r[4], __fmul_rn(q.x, q.x));
    r[5] = __fadd_rn(r[5], __fmul_rn(q.y, q.y));
    r[6] = __fadd_rn(r[6], __fmul_rn(q.z, q.z));
    r[7] = __fadd_rn(r[7], __fmul_rn(q.w, q.w));
  }
  return __fadd_rn(__fadd_rn(__fadd_rn(r[0], r[1]), __fadd_rn(r[2], r[3])),
                   __fadd_rn(__fadd_rn(r[4], r[5]), __fadd_rn(r[6], r[7])));
}

// ---------------- prep: z [B,C,H,W] -> resid [N,C] ----------------
__global__ void k_ztrans(const float* __restrict__ z, float* __restrict__ resid) {
  __shared__ float tile[32][33];
  int b = blockIdx.z, c0 = blockIdx.y * 32, hw0 = blockIdx.x * 32;
  int tx = threadIdx.x & 31, ty = threadIdx.x >> 5;
  for (int i = ty; i < 32; i += 8)
    tile[i][tx] = z[((size_t)b * CC + c0 + i) * HWt + hw0 + tx];
  __syncthreads();
  for (int i = ty; i < 32; i += 8)
    resid[((size_t)b * HWt + hw0 + i) * CC + c0 + tx] = tile[tx][i];
}

// ---------------- prep: cb [K,C] -> cbT [C,K] ----------------
__global__ void k_cbtrans(const float* __restrict__ cb, float* __restrict__ cbT) {
  __shared__ float tile[32][33];
  int k0 = blockIdx.x * 32, c0 = blockIdx.y * 32;
  int tx = threadIdx.x & 31, ty = threadIdx.x >> 5;
  for (int i = ty; i < 32; i += 8)
    tile[i][tx] = cb[(size_t)(k0 + i) * CC + c0 + tx];
  __syncthreads();
  for (int i = ty; i < 32; i += 8)
    cbT[(size_t)(c0 + i) * KK + k0 + tx] = tile[tx][i];
}

// ---------------- B_k = np.sum(cb**2, axis=1) bit-exact ----------------
__global__ void k_bnorm(const float* __restrict__ cb, float* __restrict__ Bcol) {
  int k = blockIdx.x * 256 + threadIdx.x;
  if (k >= KK) return;
  const float4* row = (const float4*)(cb + (size_t)k * CC);
  Bcol[k] = __fadd_rn(pw128sq(row), pw128sq(row + 32));
}

// ---------------- A_n = np.sum(resid**2, axis=1) bit-exact ----------------
__global__ void k_anorm(const float* __restrict__ resid, float* __restrict__ Arow) {
  int n = blockIdx.x * 256 + threadIdx.x;
  if (n >= NN) return;
  const float4* row = (const float4*)(resid + (size_t)n * CC);
  Arow[n] = __fadd_rn(pw128sq(row), pw128sq(row + 32));
}

__global__ void k_zero(int* counts) {
  int t = blockIdx.x * 256 + threadIdx.x;
  if (t < KK) counts[t] = 0;
}

// ---------------- bulk: replicate np fp32 dists + first-argmin ----------------
// d[n,k] = fl32( fl32(A_n + B_k) - 2*M ), M = sequential fp32 FMA chain over c (BLAS order).
// block = 256 = 4 waves; wave owns 16 rows; lanes sweep 64 codes/iter.
__global__ __launch_bounds__(256) void k_bulk(const float* __restrict__ resid,
                                              const float* __restrict__ cbT,
                                              const float* __restrict__ Arow,
                                              const float* __restrict__ Bcol,
                                              int* __restrict__ idxAll,
                                              float* __restrict__ idxOut,
                                              int* __restrict__ counts, int depth) {
  int wave = threadIdx.x >> 6;
  int lane = threadIdx.x & 63;
  int rowBase = (blockIdx.x * 4 + wave) * 16;
  const float4* zr = (const float4*)(resid + (size_t)rowBase * CC);

  float aval[16];
#pragma unroll
  for (int r = 0; r < 16; ++r) aval[r] = Arow[rowBase + r];

  float v1[16];
  int i1[16];
#pragma unroll
  for (int r = 0; r < 16; ++r) { v1[r] = INFINITY; i1[r] = 0x7fffffff; }

  for (int it = 0; it < KK / 64; ++it) {
    int k = it * 64 + lane;
    float bk = Bcol[k];
    float acc[16];
#pragma unroll
    for (int r = 0; r < 16; ++r) acc[r] = 0.f;
    const float* col = cbT + k;
    for (int c = 0; c < CC; c += 4) {
      float e0 = col[(size_t)(c + 0) * KK];
      float e1 = col[(size_t)(c + 1) * KK];
      float e2 = col[(size_t)(c + 2) * KK];
      float e3 = col[(size_t)(c + 3) * KK];
#pragma unroll
      for (int r = 0; r < 16; ++r) {
        float4 z4 = zr[r * (CC / 4) + (c >> 2)];
        acc[r] = fmaf(z4.x, e0, acc[r]);   // strict c-ascending FMA chain (sgemm order)
        acc[r] = fmaf(z4.y, e1, acc[r]);
        acc[r] = fmaf(z4.z, e2, acc[r]);
        acc[r] = fmaf(z4.w, e3, acc[r]);
      }
    }
#pragma unroll
    for (int r = 0; r < 16; ++r) {
      float Cv = __fadd_rn(aval[r], bk);                 // fl32(A + B)
      float s  = __fsub_rn(Cv, __fadd_rn(acc[r], acc[r]));  // fl32(C - 2M), x2 exact
      if (s < v1[r] || (s == v1[r] && k < i1[r])) { v1[r] = s; i1[r] = k; }
    }
  }
  // cross-lane first-argmin merge, lexicographic (value, index)
#pragma unroll
  for (int r = 0; r < 16; ++r) {
    float a = v1[r];
    int ai = i1[r];
    for (int m = 1; m < 64; m <<= 1) {
      float c = __shfl_xor(a, m);
      int ci = __shfl_xor(ai, m);
      if (c < a || (c == a && ci < ai)) { a = c; ai = ci; }
    }
    if (lane == 0) {
      int row = rowBase + r;
      idxAll[depth * NN + row] = ai;
      idxOut[row] = (float)ai;
      atomicAdd(counts + ai, 1);
    }
  }
}

// ------- update: resid -= q (fp32, np order), cum[d] = cum[d-1] + q, zst at d=3 -------
__global__ void k_update(const float* __restrict__ cb, const int* __restrict__ idxAll,
                         float* __restrict__ resid, float* __restrict__ cum,
                         float* __restrict__ zst, int depth) {
  __shared__ float qt[32][33];
  __shared__ float rt[32][33];
  int b = blockIdx.z, c0 = blockIdx.y * 32, hw0 = blockIdx.x * 32;
  int tx = threadIdx.x & 31, ty = threadIdx.x >> 5;
  const int* idx = idxAll + depth * NN;
  for (int i = ty; i < 32; i += 8) {
    int n = b * HWt + hw0 + i;
    int kk = idx[n];
    size_t fo = (size_t)n * CC + c0 + tx;
    float q = cb[(size_t)kk * CC + c0 + tx];
    float r = __fsub_rn(resid[fo], q);
    resid[fo] = r;
    qt[i][tx] = q;
    rt[i][tx] = r;
  }
  __syncthreads();
  const size_t PLANE = (size_t)NN * CC;
  for (int i = ty; i < 32; i += 8) {
    size_t oo = ((size_t)b * CC + c0 + i) * HWt + hw0 + tx;
    float q = qt[tx][i];
    float prevv = (depth == 0) ? 0.f : cum[(size_t)(depth - 1) * PLANE + oo];
    cum[(size_t)depth * PLANE + oo] = __fadd_rn(prevv, q);
    if (depth == 3) zst[oo] = rt[tx][i];
  }
}

// ---------------- perplexity ----------------
__global__ void k_perp(const int* __restrict__ counts, float* __restrict__ out) {
  __shared__ double sh[256];
  double s = 0.0;
  for (int k = threadIdx.x; k < KK; k += 256) {
    int c = counts[k];
    if (c > 0) {
      double p = (double)c / (double)(RQDEPTH * NN);
      s += p * log(p);
    }
  }
  sh[threadIdx.x] = s;
  __syncthreads();
  for (int st = 128; st; st >>= 1) {
    if (threadIdx.x < st) sh[threadIdx.x] += sh[threadIdx.x + st];
    __syncthreads();
  }
  if (threadIdx.x == 0) out[0] = (float)exp(-sh[0]);
}

extern "C" void kernel_launch(void* const* d_in, const int* in_sizes, int n_in,
                              void* d_out, int out_size, void* d_ws, size_t ws_size,
                              hipStream_t stream) {
  const float* z  = (const float*)d_in[0];
  const float* cb = (const float*)d_in[1];
  float* out = (float*)d_out;
  const size_t PLANE = (size_t)NN * CC;          // 8,388,608
  float* cum  = out;                             // [4][B][C][H][W]
  float* zst  = out + (size_t)RQDEPTH * PLANE;   // [B][C][H][W]
  float* idxo = zst + PLANE;                     // [4][N]
  float* perp = idxo + (size_t)RQDEPTH * NN;     // scalar

  float* resid = (float*)d_ws;                   // N*C
  float* cbT   = resid + PLANE;                  // C*K
  float* Arow  = cbT + (size_t)CC * KK;          // N
  float* Bcol  = Arow + NN;                      // K
  int* idxAll  = (int*)(Bcol + KK);              // D*N
  int* counts  = idxAll + RQDEPTH * NN;          // K

  dim3 tgrid(HWt / 32, CC / 32, BB);             // 32 x 8 x 32
  k_ztrans<<<tgrid, 256, 0, stream>>>(z, resid);
  dim3 cgrid(KK / 32, CC / 32);
  k_cbtrans<<<cgrid, 256, 0, stream>>>(cb, cbT);
  k_bnorm<<<KK / 256, 256, 0, stream>>>(cb, Bcol);
  k_zero<<<(KK + 255) / 256, 256, 0, stream>>>(counts);

  for (int d = 0; d < RQDEPTH; ++d) {
    k_anorm<<<NN / 256, 256, 0, stream>>>(resid, Arow);
    k_bulk<<<NN / 64, 256, 0, stream>>>(resid, cbT, Arow, Bcol, idxAll,
                                        idxo + (size_t)d * NN, counts, d);
    k_update<<<tgrid, 256, 0, stream>>>(cb, idxAll, resid, cum, zst, d);
  }
  k_perp<<<1, 256, 0, stream>>>(counts, perp);
}

// Round 3
// 5386.568 us; speedup vs baseline: 2.1429x; 2.1429x over previous
//
#include <hip/hip_runtime.h>
#include <math.h>

#define BB 32
#define CC 256
#define HWt 1024          // H*W
#define NN 32768          // B*H*W
#define KK 2048
#define RQDEPTH 4

// ===== numpy pairwise sum-of-squares, blocksize-128 tree, bit-exact =====
__device__ __forceinline__ float pw128sq(const float4* __restrict__ a4) {
  float r[8];
  {
    float4 p = a4[0], q = a4[1];
    r[0] = __fmul_rn(p.x, p.x); r[1] = __fmul_rn(p.y, p.y);
    r[2] = __fmul_rn(p.z, p.z); r[3] = __fmul_rn(p.w, p.w);
    r[4] = __fmul_rn(q.x, q.x); r[5] = __fmul_rn(q.y, q.y);
    r[6] = __fmul_rn(q.z, q.z); r[7] = __fmul_rn(q.w, q.w);
  }
  for (int i = 1; i < 16; ++i) {
    float4 p = a4[2 * i], q = a4[2 * i + 1];
    r[0] = __fadd_rn(r[0], __fmul_rn(p.x, p.x));
    r[1] = __fadd_rn(r[1], __fmul_rn(p.y, p.y));
    r[2] = __fadd_rn(r[2], __fmul_rn(p.z, p.z));
    r[3] = __fadd_rn(r[3], __fmul_rn(p.w, p.w));
    r[4] = __fadd_rn(r[4], __fmul_rn(q.x, q.x));
    r[5] = __fadd_rn(r[5], __fmul_rn(q.y, q.y));
    r[6] = __fadd_rn(r[6], __fmul_rn(q.z, q.z));
    r[7] = __fadd_rn(r[7], __fmul_rn(q.w, q.w));
  }
  return __fadd_rn(__fadd_rn(__fadd_rn(r[0], r[1]), __fadd_rn(r[2], r[3])),
                   __fadd_rn(__fadd_rn(r[4], r[5]), __fadd_rn(r[6], r[7])));
}

// ---------------- prep: z [B,C,H,W] -> resid [N,C] ----------------
__global__ void k_ztrans(const float* __restrict__ z, float* __restrict__ resid) {
  __shared__ float tile[32][33];
  int b = blockIdx.z, c0 = blockIdx.y * 32, hw0 = blockIdx.x * 32;
  int tx = threadIdx.x & 31, ty = threadIdx.x >> 5;
  for (int i = ty; i < 32; i += 8)
    tile[i][tx] = z[((size_t)b * CC + c0 + i) * HWt + hw0 + tx];
  __syncthreads();
  for (int i = ty; i < 32; i += 8)
    resid[((size_t)b * HWt + hw0 + i) * CC + c0 + tx] = tile[tx][i];
}

// ---------------- prep: cb [K,C] -> cbT [C,K] ----------------
__global__ void k_cbtrans(const float* __restrict__ cb, float* __restrict__ cbT) {
  __shared__ float tile[32][33];
  int k0 = blockIdx.x * 32, c0 = blockIdx.y * 32;
  int tx = threadIdx.x & 31, ty = threadIdx.x >> 5;
  for (int i = ty; i < 32; i += 8)
    tile[i][tx] = cb[(size_t)(k0 + i) * CC + c0 + tx];
  __syncthreads();
  for (int i = ty; i < 32; i += 8)
    cbT[(size_t)(c0 + i) * KK + k0 + tx] = tile[tx][i];
}

// ---------------- B_k = np.sum(cb**2, axis=1) bit-exact ----------------
__global__ void k_bnorm(const float* __restrict__ cb, float* __restrict__ Bcol) {
  int k = blockIdx.x * 256 + threadIdx.x;
  if (k >= KK) return;
  const float4* row = (const float4*)(cb + (size_t)k * CC);
  Bcol[k] = __fadd_rn(pw128sq(row), pw128sq(row + 32));
}

// ---------------- A_n = np.sum(resid**2, axis=1) bit-exact ----------------
__global__ void k_anorm(const float* __restrict__ resid, float* __restrict__ Arow) {
  int n = blockIdx.x * 256 + threadIdx.x;
  if (n >= NN) return;
  const float4* row = (const float4*)(resid + (size_t)n * CC);
  Arow[n] = __fadd_rn(pw128sq(row), pw128sq(row + 32));
}

__global__ void k_zero(int* counts) {
  int t = blockIdx.x * 256 + threadIdx.x;
  if (t < KK) counts[t] = 0;
}

// ---------------- bulk: np fp32 dists + first-argmin, k split across waves ----------
// Block = 256 thr = 4 waves, 16 rows. Wave w: rows row0 = blk*16 + (w&1)*8 (8 rows),
// codes k in [ (w>>1)*1024 , +1024 ). z is wave-uniform -> scalar loads feeding
// v_fmac src0; cbT loads are lane-coalesced. Lex-(v,i) merge in LDS is exact
// first-argmin. FMA chain per (n,k) identical to the R2 bit-exact kernel.
__global__ __launch_bounds__(256, 6) void k_bulk(const float* __restrict__ resid,
                                                 const float* __restrict__ cbT,
                                                 const float* __restrict__ Arow,
                                                 const float* __restrict__ Bcol,
                                                 int* __restrict__ idxAll,
                                                 float* __restrict__ idxOut,
                                                 int* __restrict__ counts, int depth) {
  __shared__ float sv[4][8];
  __shared__ int   si[4][8];
  const int wave = __builtin_amdgcn_readfirstlane((int)(threadIdx.x >> 6));
  const int lane = threadIdx.x & 63;
  const int rowHalf = wave & 1, khalf = wave >> 1;
  const int row0 = blockIdx.x * 16 + rowHalf * 8;
  const float* zb = resid + (size_t)row0 * CC;   // wave-uniform base

  float av[8];
#pragma unroll
  for (int r = 0; r < 8; ++r) av[r] = Arow[row0 + r];   // uniform -> SGPR

  float v1[8]; int i1[8];
#pragma unroll
  for (int r = 0; r < 8; ++r) { v1[r] = INFINITY; i1[r] = 0x7fffffff; }

  for (int it = 0; it < 16; ++it) {
    const int k = khalf * 1024 + it * 64 + lane;
    const float bk = Bcol[k];
    float acc[8];
#pragma unroll
    for (int r = 0; r < 8; ++r) acc[r] = 0.f;
    const float* col = cbT + k;
#pragma unroll 4
    for (int c4 = 0; c4 < CC / 4; ++c4) {
      const int c = c4 * 4;
      float e0 = col[(size_t)(c + 0) * KK];
      float e1 = col[(size_t)(c + 1) * KK];
      float e2 = col[(size_t)(c + 2) * KK];
      float e3 = col[(size_t)(c + 3) * KK];
#pragma unroll
      for (int r = 0; r < 8; ++r) {
        float4 z4 = ((const float4*)(zb + r * CC))[c4];   // uniform -> s_load_dwordx4
        acc[r] = fmaf(z4.x, e0, acc[r]);   // strict c-ascending chain (sgemm order)
        acc[r] = fmaf(z4.y, e1, acc[r]);
        acc[r] = fmaf(z4.z, e2, acc[r]);
        acc[r] = fmaf(z4.w, e3, acc[r]);
      }
    }
#pragma unroll
    for (int r = 0; r < 8; ++r) {
      float Cv = __fadd_rn(av[r], bk);                    // fl32(A + B)
      float s  = __fsub_rn(Cv, __fadd_rn(acc[r], acc[r])); // fl32(C - 2M)
      if (s < v1[r] || (s == v1[r] && k < i1[r])) { v1[r] = s; i1[r] = k; }
    }
  }
  // cross-lane first-argmin per row
#pragma unroll
  for (int r = 0; r < 8; ++r) {
    float a = v1[r]; int ai = i1[r];
    for (int m = 1; m < 64; m <<= 1) {
      float c = __shfl_xor(a, m); int ci = __shfl_xor(ai, m);
      if (c < a || (c == a && ci < ai)) { a = c; ai = ci; }
    }
    if (lane == 0) { sv[wave][r] = a; si[wave][r] = ai; }
  }
  __syncthreads();
  // merge the two k-halves per row (k-ascending lex merge = exact first-argmin)
  if (threadIdx.x < 16) {
    int rh = (int)threadIdx.x >> 3, rl = (int)threadIdx.x & 7;
    float avv = sv[rh][rl]; int aii = si[rh][rl];          // khalf 0
    float bvv = sv[2 + rh][rl]; int bii = si[2 + rh][rl];  // khalf 1
    int wi = (bvv < avv || (bvv == avv && bii < aii)) ? bii : aii;
    int n = blockIdx.x * 16 + (int)threadIdx.x;
    idxAll[depth * NN + n] = wi;
    idxOut[n] = (float)wi;
    atomicAdd(counts + wi, 1);
  }
}

// ------- update: resid -= q (fp32, np order), cum[d] = cum[d-1] + q, zst at d=3 -------
__global__ void k_update(const float* __restrict__ cb, const int* __restrict__ idxAll,
                         float* __restrict__ resid, float* __restrict__ cum,
                         float* __restrict__ zst, int depth) {
  __shared__ float qt[32][33];
  __shared__ float rt[32][33];
  int b = blockIdx.z, c0 = blockIdx.y * 32, hw0 = blockIdx.x * 32;
  int tx = threadIdx.x & 31, ty = threadIdx.x >> 5;
  const int* idx = idxAll + depth * NN;
  for (int i = ty; i < 32; i += 8) {
    int n = b * HWt + hw0 + i;
    int kk = idx[n];
    size_t fo = (size_t)n * CC + c0 + tx;
    float q = cb[(size_t)kk * CC + c0 + tx];
    float r = __fsub_rn(resid[fo], q);
    resid[fo] = r;
    qt[i][tx] = q;
    rt[i][tx] = r;
  }
  __syncthreads();
  const size_t PLANE = (size_t)NN * CC;
  for (int i = ty; i < 32; i += 8) {
    size_t oo = ((size_t)b * CC + c0 + i) * HWt + hw0 + tx;
    float q = qt[tx][i];
    float prevv = (depth == 0) ? 0.f : cum[(size_t)(depth - 1) * PLANE + oo];
    cum[(size_t)depth * PLANE + oo] = __fadd_rn(prevv, q);
    if (depth == 3) zst[oo] = rt[tx][i];
  }
}

// ---------------- perplexity ----------------
__global__ void k_perp(const int* __restrict__ counts, float* __restrict__ out) {
  __shared__ double sh[256];
  double s = 0.0;
  for (int k = threadIdx.x; k < KK; k += 256) {
    int c = counts[k];
    if (c > 0) {
      double p = (double)c / (double)(RQDEPTH * NN);
      s += p * log(p);
    }
  }
  sh[threadIdx.x] = s;
  __syncthreads();
  for (int st = 128; st; st >>= 1) {
    if (threadIdx.x < st) sh[threadIdx.x] += sh[threadIdx.x + st];
    __syncthreads();
  }
  if (threadIdx.x == 0) out[0] = (float)exp(-sh[0]);
}

extern "C" void kernel_launch(void* const* d_in, const int* in_sizes, int n_in,
                              void* d_out, int out_size, void* d_ws, size_t ws_size,
                              hipStream_t stream) {
  const float* z  = (const float*)d_in[0];
  const float* cb = (const float*)d_in[1];
  float* out = (float*)d_out;
  const size_t PLANE = (size_t)NN * CC;          // 8,388,608
  float* cum  = out;                             // [4][B][C][H][W]
  float* zst  = out + (size_t)RQDEPTH * PLANE;   // [B][C][H][W]
  float* idxo = zst + PLANE;                     // [4][N]
  float* perp = idxo + (size_t)RQDEPTH * NN;     // scalar

  float* resid = (float*)d_ws;                   // N*C
  float* cbT   = resid + PLANE;                  // C*K
  float* Arow  = cbT + (size_t)CC * KK;          // N
  float* Bcol  = Arow + NN;                      // K
  int* idxAll  = (int*)(Bcol + KK);              // D*N
  int* counts  = idxAll + RQDEPTH * NN;          // K

  dim3 tgrid(HWt / 32, CC / 32, BB);             // 32 x 8 x 32
  k_ztrans<<<tgrid, 256, 0, stream>>>(z, resid);
  dim3 cgrid(KK / 32, CC / 32);
  k_cbtrans<<<cgrid, 256, 0, stream>>>(cb, cbT);
  k_bnorm<<<KK / 256, 256, 0, stream>>>(cb, Bcol);
  k_zero<<<(KK + 255) / 256, 256, 0, stream>>>(counts);

  for (int d = 0; d < RQDEPTH; ++d) {
    k_anorm<<<NN / 256, 256, 0, stream>>>(resid, Arow);
    k_bulk<<<NN / 16, 256, 0, stream>>>(resid, cbT, Arow, Bcol, idxAll,
                                        idxo + (size_t)d * NN, counts, d);
    k_update<<<tgrid, 256, 0, stream>>>(cb, idxAll, resid, cum, zst, d);
  }
  k_perp<<<1, 256, 0, stream>>>(counts, perp);
}

// Round 4
// 3098.553 us; speedup vs baseline: 3.7252x; 1.7384x over previous
//
#include <hip/hip_runtime.h>
#include <math.h>

#define BB 32
#define CC 256
#define HWt 1024          // H*W
#define NN 32768          // B*H*W
#define KK 2048
#define RQDEPTH 4

// ===== numpy pairwise sum-of-squares, blocksize-128 tree, bit-exact =====
__device__ __forceinline__ float pw128sq(const float4* __restrict__ a4) {
  float r[8];
  {
    float4 p = a4[0], q = a4[1];
    r[0] = __fmul_rn(p.x, p.x); r[1] = __fmul_rn(p.y, p.y);
    r[2] = __fmul_rn(p.z, p.z); r[3] = __fmul_rn(p.w, p.w);
    r[4] = __fmul_rn(q.x, q.x); r[5] = __fmul_rn(q.y, q.y);
    r[6] = __fmul_rn(q.z, q.z); r[7] = __fmul_rn(q.w, q.w);
  }
  for (int i = 1; i < 16; ++i) {
    float4 p = a4[2 * i], q = a4[2 * i + 1];
    r[0] = __fadd_rn(r[0], __fmul_rn(p.x, p.x));
    r[1] = __fadd_rn(r[1], __fmul_rn(p.y, p.y));
    r[2] = __fadd_rn(r[2], __fmul_rn(p.z, p.z));
    r[3] = __fadd_rn(r[3], __fmul_rn(p.w, p.w));
    r[4] = __fadd_rn(r[4], __fmul_rn(q.x, q.x));
    r[5] = __fadd_rn(r[5], __fmul_rn(q.y, q.y));
    r[6] = __fadd_rn(r[6], __fmul_rn(q.z, q.z));
    r[7] = __fadd_rn(r[7], __fmul_rn(q.w, q.w));
  }
  return __fadd_rn(__fadd_rn(__fadd_rn(r[0], r[1]), __fadd_rn(r[2], r[3])),
                   __fadd_rn(__fadd_rn(r[4], r[5]), __fadd_rn(r[6], r[7])));
}

// ---------------- prep: z [B,C,H,W] -> resid [N,C] ----------------
__global__ void k_ztrans(const float* __restrict__ z, float* __restrict__ resid) {
  __shared__ float tile[32][33];
  int b = blockIdx.z, c0 = blockIdx.y * 32, hw0 = blockIdx.x * 32;
  int tx = threadIdx.x & 31, ty = threadIdx.x >> 5;
  for (int i = ty; i < 32; i += 8)
    tile[i][tx] = z[((size_t)b * CC + c0 + i) * HWt + hw0 + tx];
  __syncthreads();
  for (int i = ty; i < 32; i += 8)
    resid[((size_t)b * HWt + hw0 + i) * CC + c0 + tx] = tile[tx][i];
}

// ---------------- prep: cb [K,C] -> cbT [C,K] ----------------
__global__ void k_cbtrans(const float* __restrict__ cb, float* __restrict__ cbT) {
  __shared__ float tile[32][33];
  int k0 = blockIdx.x * 32, c0 = blockIdx.y * 32;
  int tx = threadIdx.x & 31, ty = threadIdx.x >> 5;
  for (int i = ty; i < 32; i += 8)
    tile[i][tx] = cb[(size_t)(k0 + i) * CC + c0 + tx];
  __syncthreads();
  for (int i = ty; i < 32; i += 8)
    cbT[(size_t)(c0 + i) * KK + k0 + tx] = tile[tx][i];
}

// ---------------- B_k = np.sum(cb**2, axis=1) bit-exact ----------------
__global__ void k_bnorm(const float* __restrict__ cb, float* __restrict__ Bcol) {
  int k = blockIdx.x * 256 + threadIdx.x;
  if (k >= KK) return;
  const float4* row = (const float4*)(cb + (size_t)k * CC);
  Bcol[k] = __fadd_rn(pw128sq(row), pw128sq(row + 32));
}

// ---------------- A_n = np.sum(resid**2, axis=1) bit-exact ----------------
__global__ void k_anorm(const float* __restrict__ resid, float* __restrict__ Arow) {
  int n = blockIdx.x * 256 + threadIdx.x;
  if (n >= NN) return;
  const float4* row = (const float4*)(resid + (size_t)n * CC);
  Arow[n] = __fadd_rn(pw128sq(row), pw128sq(row + 32));
}

__global__ void k_zero(int* counts) {
  int t = blockIdx.x * 256 + threadIdx.x;
  if (t < KK) counts[t] = 0;
}

// ---------------- bulk: np fp32 dists + first-argmin ----------------
// Block = 4 waves, ALL waves share the same 16 rows (z via scalar loads, shared
// through the scalar cache); wave w owns k-quarter [w*512, (w+1)*512).
// cbT addressed as uniform-base + [k]  -> scalar base adds + fixed v-offset.
// (dist,k) packed into u64 (dist > 0 always: it's ||r - e||^2 + rounding), so
// 64-bit min == exact lexicographic (value asc, index asc) first-argmin.
// Per-(n,k) fp32 chain identical to the verified bit-exact kernel.
__global__ __launch_bounds__(256, 6) void k_bulk(const float* __restrict__ resid,
                                                 const float* __restrict__ cbT,
                                                 const float* __restrict__ Arow,
                                                 const float* __restrict__ Bcol,
                                                 int* __restrict__ idxAll,
                                                 float* __restrict__ idxOut,
                                                 int* __restrict__ counts, int depth) {
  __shared__ unsigned long long sm[4][16];
  const int wave = __builtin_amdgcn_readfirstlane((int)(threadIdx.x >> 6));
  const int lane = threadIdx.x & 63;
  const int row0 = blockIdx.x * 16;
  const float* zb = resid + (size_t)row0 * CC;   // wave-uniform base

  float av[16];
#pragma unroll
  for (int r = 0; r < 16; ++r) av[r] = Arow[row0 + r];   // uniform -> SGPR

  unsigned long long best[16];
#pragma unroll
  for (int r = 0; r < 16; ++r) best[r] = ~0ull;

  for (int it = 0; it < 8; ++it) {
    const int k = wave * 512 + it * 64 + lane;
    const float bk = Bcol[k];
    float acc[16];
#pragma unroll
    for (int r = 0; r < 16; ++r) acc[r] = 0.f;

    for (int c4 = 0; c4 < CC / 4; ++c4) {
      // uniform base pointers -> global_load_dword v, v_k4, s[base]
      const float* p0 = cbT + (size_t)(4 * c4 + 0) * KK;
      const float* p1 = cbT + (size_t)(4 * c4 + 1) * KK;
      const float* p2 = cbT + (size_t)(4 * c4 + 2) * KK;
      const float* p3 = cbT + (size_t)(4 * c4 + 3) * KK;
      float e0 = p0[k], e1 = p1[k], e2 = p2[k], e3 = p3[k];
#pragma unroll
      for (int r = 0; r < 16; ++r) {
        const float4 z4 = *(const float4*)(zb + (size_t)r * CC + 4 * c4);  // uniform -> s_load
        acc[r] = fmaf(z4.x, e0, acc[r]);   // strict c-ascending chain (sgemm order)
        acc[r] = fmaf(z4.y, e1, acc[r]);
        acc[r] = fmaf(z4.z, e2, acc[r]);
        acc[r] = fmaf(z4.w, e3, acc[r]);
      }
    }
#pragma unroll
    for (int r = 0; r < 16; ++r) {
      float Cv = __fadd_rn(av[r], bk);                      // fl32(A + B)
      float s  = __fsub_rn(Cv, __fadd_rn(acc[r], acc[r]));  // fl32(C - 2M)
      unsigned long long pk =
          ((unsigned long long)__float_as_uint(s) << 32) | (unsigned int)k;
      if (pk < best[r]) best[r] = pk;
    }
  }
  // cross-lane 64-bit min per row (exact lex first-argmin)
#pragma unroll
  for (int r = 0; r < 16; ++r) {
    unsigned long long b = best[r];
    for (int m = 1; m < 64; m <<= 1) {
      unsigned long long o = __shfl_xor(b, m);
      if (o < b) b = o;
    }
    if (lane == 0) sm[wave][r] = b;
  }
  __syncthreads();
  // merge the four k-quarters per row
  if (threadIdx.x < 16) {
    unsigned long long b = sm[0][threadIdx.x];
    if (sm[1][threadIdx.x] < b) b = sm[1][threadIdx.x];
    if (sm[2][threadIdx.x] < b) b = sm[2][threadIdx.x];
    if (sm[3][threadIdx.x] < b) b = sm[3][threadIdx.x];
    int wi = (int)(unsigned int)(b & 0xffffffffu);
    int n = row0 + (int)threadIdx.x;
    idxAll[depth * NN + n] = wi;
    idxOut[n] = (float)wi;
    atomicAdd(counts + wi, 1);
  }
}

// ------- update: resid -= q (fp32, np order), cum[d] = cum[d-1] + q, zst at d=3 -------
__global__ void k_update(const float* __restrict__ cb, const int* __restrict__ idxAll,
                         float* __restrict__ resid, float* __restrict__ cum,
                         float* __restrict__ zst, int depth) {
  __shared__ float qt[32][33];
  __shared__ float rt[32][33];
  int b = blockIdx.z, c0 = blockIdx.y * 32, hw0 = blockIdx.x * 32;
  int tx = threadIdx.x & 31, ty = threadIdx.x >> 5;
  const int* idx = idxAll + depth * NN;
  for (int i = ty; i < 32; i += 8) {
    int n = b * HWt + hw0 + i;
    int kk = idx[n];
    size_t fo = (size_t)n * CC + c0 + tx;
    float q = cb[(size_t)kk * CC + c0 + tx];
    float r = __fsub_rn(resid[fo], q);
    resid[fo] = r;
    qt[i][tx] = q;
    rt[i][tx] = r;
  }
  __syncthreads();
  const size_t PLANE = (size_t)NN * CC;
  for (int i = ty; i < 32; i += 8) {
    size_t oo = ((size_t)b * CC + c0 + i) * HWt + hw0 + tx;
    float q = qt[tx][i];
    float prevv = (depth == 0) ? 0.f : cum[(size_t)(depth - 1) * PLANE + oo];
    cum[(size_t)depth * PLANE + oo] = __fadd_rn(prevv, q);
    if (depth == 3) zst[oo] = rt[tx][i];
  }
}

// ---------------- perplexity ----------------
__global__ void k_perp(const int* __restrict__ counts, float* __restrict__ out) {
  __shared__ double sh[256];
  double s = 0.0;
  for (int k = threadIdx.x; k < KK; k += 256) {
    int c = counts[k];
    if (c > 0) {
      double p = (double)c / (double)(RQDEPTH * NN);
      s += p * log(p);
    }
  }
  sh[threadIdx.x] = s;
  __syncthreads();
  for (int st = 128; st; st >>= 1) {
    if (threadIdx.x < st) sh[threadIdx.x] += sh[threadIdx.x + st];
    __syncthreads();
  }
  if (threadIdx.x == 0) out[0] = (float)exp(-sh[0]);
}

extern "C" void kernel_launch(void* const* d_in, const int* in_sizes, int n_in,
                              void* d_out, int out_size, void* d_ws, size_t ws_size,
                              hipStream_t stream) {
  const float* z  = (const float*)d_in[0];
  const float* cb = (const float*)d_in[1];
  float* out = (float*)d_out;
  const size_t PLANE = (size_t)NN * CC;          // 8,388,608
  float* cum  = out;                             // [4][B][C][H][W]
  float* zst  = out + (size_t)RQDEPTH * PLANE;   // [B][C][H][W]
  float* idxo = zst + PLANE;                     // [4][N]
  float* perp = idxo + (size_t)RQDEPTH * NN;     // scalar

  float* resid = (float*)d_ws;                   // N*C
  float* cbT   = resid + PLANE;                  // C*K
  float* Arow  = cbT + (size_t)CC * KK;          // N
  float* Bcol  = Arow + NN;                      // K
  int* idxAll  = (int*)(Bcol + KK);              // D*N
  int* counts  = idxAll + RQDEPTH * NN;          // K

  dim3 tgrid(HWt / 32, CC / 32, BB);             // 32 x 8 x 32
  k_ztrans<<<tgrid, 256, 0, stream>>>(z, resid);
  dim3 cgrid(KK / 32, CC / 32);
  k_cbtrans<<<cgrid, 256, 0, stream>>>(cb, cbT);
  k_bnorm<<<KK / 256, 256, 0, stream>>>(cb, Bcol);
  k_zero<<<(KK + 255) / 256, 256, 0, stream>>>(counts);

  for (int d = 0; d < RQDEPTH; ++d) {
    k_anorm<<<NN / 256, 256, 0, stream>>>(resid, Arow);
    k_bulk<<<NN / 16, 256, 0, stream>>>(resid, cbT, Arow, Bcol, idxAll,
                                        idxo + (size_t)d * NN, counts, d);
    k_update<<<tgrid, 256, 0, stream>>>(cb, idxAll, resid, cum, zst, d);
  }
  k_perp<<<1, 256, 0, stream>>>(counts, perp);
}

// Round 5
// 1809.779 us; speedup vs baseline: 6.3780x; 1.7121x over previous
//
#include <hip/hip_runtime.h>
#include <math.h>

#define BB 32
#define CC 256
#define HWt 1024          // H*W
#define NN 32768          // B*H*W
#define KK 2048
#define RQDEPTH 4

// ===== numpy pairwise sum-of-squares, blocksize-128 tree, bit-exact =====
__device__ __forceinline__ float pw128sq(const float4* __restrict__ a4) {
  float r[8];
  {
    float4 p = a4[0], q = a4[1];
    r[0] = __fmul_rn(p.x, p.x); r[1] = __fmul_rn(p.y, p.y);
    r[2] = __fmul_rn(p.z, p.z); r[3] = __fmul_rn(p.w, p.w);
    r[4] = __fmul_rn(q.x, q.x); r[5] = __fmul_rn(q.y, q.y);
    r[6] = __fmul_rn(q.z, q.z); r[7] = __fmul_rn(q.w, q.w);
  }
  for (int i = 1; i < 16; ++i) {
    float4 p = a4[2 * i], q = a4[2 * i + 1];
    r[0] = __fadd_rn(r[0], __fmul_rn(p.x, p.x));
    r[1] = __fadd_rn(r[1], __fmul_rn(p.y, p.y));
    r[2] = __fadd_rn(r[2], __fmul_rn(p.z, p.z));
    r[3] = __fadd_rn(r[3], __fmul_rn(p.w, p.w));
    r[4] = __fadd_rn(r[4], __fmul_rn(q.x, q.x));
    r[5] = __fadd_rn(r[5], __fmul_rn(q.y, q.y));
    r[6] = __fadd_rn(r[6], __fmul_rn(q.z, q.z));
    r[7] = __fadd_rn(r[7], __fmul_rn(q.w, q.w));
  }
  return __fadd_rn(__fadd_rn(__fadd_rn(r[0], r[1]), __fadd_rn(r[2], r[3])),
                   __fadd_rn(__fadd_rn(r[4], r[5]), __fadd_rn(r[6], r[7])));
}

// ---------------- prep: z [B,C,H,W] -> resid [N,C] ----------------
__global__ void k_ztrans(const float* __restrict__ z, float* __restrict__ resid) {
  __shared__ float tile[32][33];
  int b = blockIdx.z, c0 = blockIdx.y * 32, hw0 = blockIdx.x * 32;
  int tx = threadIdx.x & 31, ty = threadIdx.x >> 5;
  for (int i = ty; i < 32; i += 8)
    tile[i][tx] = z[((size_t)b * CC + c0 + i) * HWt + hw0 + tx];
  __syncthreads();
  for (int i = ty; i < 32; i += 8)
    resid[((size_t)b * HWt + hw0 + i) * CC + c0 + tx] = tile[tx][i];
}

// ---------------- prep: cb [K,C] -> cbT [C,K] ----------------
__global__ void k_cbtrans(const float* __restrict__ cb, float* __restrict__ cbT) {
  __shared__ float tile[32][33];
  int k0 = blockIdx.x * 32, c0 = blockIdx.y * 32;
  int tx = threadIdx.x & 31, ty = threadIdx.x >> 5;
  for (int i = ty; i < 32; i += 8)
    tile[i][tx] = cb[(size_t)(k0 + i) * CC + c0 + tx];
  __syncthreads();
  for (int i = ty; i < 32; i += 8)
    cbT[(size_t)(c0 + i) * KK + k0 + tx] = tile[tx][i];
}

// ---------------- B_k = np.sum(cb**2, axis=1) bit-exact ----------------
__global__ void k_bnorm(const float* __restrict__ cb, float* __restrict__ Bcol) {
  int k = blockIdx.x * 256 + threadIdx.x;
  if (k >= KK) return;
  const float4* row = (const float4*)(cb + (size_t)k * CC);
  Bcol[k] = __fadd_rn(pw128sq(row), pw128sq(row + 32));
}

// ---------------- A_n = np.sum(resid**2, axis=1) bit-exact ----------------
__global__ void k_anorm(const float* __restrict__ resid, float* __restrict__ Arow) {
  int n = blockIdx.x * 256 + threadIdx.x;
  if (n >= NN) return;
  const float4* row = (const float4*)(resid + (size_t)n * CC);
  Arow[n] = __fadd_rn(pw128sq(row), pw128sq(row + 32));
}

__global__ void k_zero(int* counts) {
  int t = blockIdx.x * 256 + threadIdx.x;
  if (t < KK) counts[t] = 0;
}

// ---------------- bulk: np fp32 dists + first-argmin, ILP-restructured ----------
// Block = 4 waves sharing 16 rows. Wave w owns k in [w*512,(w+1)*512), split in
// 2 passes of 256; within a pass, lane l carries k = kbase + l*4 + j (j=0..3),
// so each lane holds acc[16 rows][4 k] = 64 independent FMA chains. Outer loop
// over c4: 4 dwordx4 cbT loads + 16 uniform z s_loads feed 256 FMAs (huge ILP,
// z read once per pass instead of 8x). Per-(n,k) fp32 chain is bit-identical
// to the verified kernel: strict c-ascending fmaf, fl(A+B) - 2*acc, u64
// (dist,k) min == exact lex first-argmin (dists are always > 0 here).
__global__ __launch_bounds__(256, 4) void k_bulk(const float* __restrict__ resid,
                                                 const float* __restrict__ cbT,
                                                 const float* __restrict__ Arow,
                                                 const float* __restrict__ Bcol,
                                                 int* __restrict__ idxAll,
                                                 float* __restrict__ idxOut,
                                                 int* __restrict__ counts, int depth) {
  __shared__ unsigned long long sm[4][2][16];
  const int wave = __builtin_amdgcn_readfirstlane((int)(threadIdx.x >> 6));
  const int lane = threadIdx.x & 63;
  const int row0 = blockIdx.x * 16;
  const float* zb = resid + (size_t)row0 * CC;   // wave-uniform base

  float av[16];
#pragma unroll
  for (int r = 0; r < 16; ++r) av[r] = Arow[row0 + r];   // uniform -> SGPR

  for (int pass = 0; pass < 2; ++pass) {
    const int kbase = wave * 512 + pass * 256;
    float acc[16][4];
#pragma unroll
    for (int r = 0; r < 16; ++r)
#pragma unroll
      for (int j = 0; j < 4; ++j) acc[r][j] = 0.f;

    for (int c4 = 0; c4 < CC / 4; ++c4) {
      float e[16];  // [cs][j]
#pragma unroll
      for (int cs = 0; cs < 4; ++cs)
        *(float4*)(e + 4 * cs) =
            ((const float4*)(cbT + (size_t)(4 * c4 + cs) * KK + kbase))[lane];
#pragma unroll
      for (int r = 0; r < 16; ++r) {
        const float4 z4 = *(const float4*)(zb + (size_t)r * CC + 4 * c4);  // uniform -> s_load
#pragma unroll
        for (int j = 0; j < 4; ++j) {
          float a = acc[r][j];
          a = fmaf(z4.x, e[0 * 4 + j], a);   // strict c-ascending chain (sgemm order)
          a = fmaf(z4.y, e[1 * 4 + j], a);
          a = fmaf(z4.z, e[2 * 4 + j], a);
          a = fmaf(z4.w, e[3 * 4 + j], a);
          acc[r][j] = a;
        }
      }
    }
    // epilogue: dists + exact lex first-argmin for this pass
    float bk[4];
    *(float4*)bk = ((const float4*)(Bcol + kbase))[lane];
#pragma unroll
    for (int r = 0; r < 16; ++r) {
      unsigned long long b = ~0ull;
#pragma unroll
      for (int j = 0; j < 4; ++j) {
        float Cv = __fadd_rn(av[r], bk[j]);                      // fl32(A + B)
        float s  = __fsub_rn(Cv, __fadd_rn(acc[r][j], acc[r][j]));  // fl32(C - 2M)
        unsigned long long pk =
            ((unsigned long long)__float_as_uint(s) << 32) |
            (unsigned int)(kbase + lane * 4 + j);
        if (pk < b) b = pk;
      }
      for (int m = 1; m < 64; m <<= 1) {
        unsigned long long o = __shfl_xor(b, m);
        if (o < b) b = o;
      }
      if (lane == 0) sm[wave][pass][r] = b;
    }
  }
  __syncthreads();
  // merge 4 waves x 2 passes per row
  if (threadIdx.x < 16) {
    unsigned long long b = ~0ull;
#pragma unroll
    for (int w = 0; w < 4; ++w)
#pragma unroll
      for (int p = 0; p < 2; ++p)
        if (sm[w][p][threadIdx.x] < b) b = sm[w][p][threadIdx.x];
    int wi = (int)(unsigned int)(b & 0xffffffffu);
    int n = row0 + (int)threadIdx.x;
    idxAll[depth * NN + n] = wi;
    idxOut[n] = (float)wi;
    atomicAdd(counts + wi, 1);
  }
}

// ------- update: resid -= q (fp32, np order), cum[d] = cum[d-1] + q, zst at d=3 -------
__global__ void k_update(const float* __restrict__ cb, const int* __restrict__ idxAll,
                         float* __restrict__ resid, float* __restrict__ cum,
                         float* __restrict__ zst, int depth) {
  __shared__ float qt[32][33];
  __shared__ float rt[32][33];
  int b = blockIdx.z, c0 = blockIdx.y * 32, hw0 = blockIdx.x * 32;
  int tx = threadIdx.x & 31, ty = threadIdx.x >> 5;
  const int* idx = idxAll + depth * NN;
  for (int i = ty; i < 32; i += 8) {
    int n = b * HWt + hw0 + i;
    int kk = idx[n];
    size_t fo = (size_t)n * CC + c0 + tx;
    float q = cb[(size_t)kk * CC + c0 + tx];
    float r = __fsub_rn(resid[fo], q);
    resid[fo] = r;
    qt[i][tx] = q;
    rt[i][tx] = r;
  }
  __syncthreads();
  const size_t PLANE = (size_t)NN * CC;
  for (int i = ty; i < 32; i += 8) {
    size_t oo = ((size_t)b * CC + c0 + i) * HWt + hw0 + tx;
    float q = qt[tx][i];
    float prevv = (depth == 0) ? 0.f : cum[(size_t)(depth - 1) * PLANE + oo];
    cum[(size_t)depth * PLANE + oo] = __fadd_rn(prevv, q);
    if (depth == 3) zst[oo] = rt[tx][i];
  }
}

// ---------------- perplexity ----------------
__global__ void k_perp(const int* __restrict__ counts, float* __restrict__ out) {
  __shared__ double sh[256];
  double s = 0.0;
  for (int k = threadIdx.x; k < KK; k += 256) {
    int c = counts[k];
    if (c > 0) {
      double p = (double)c / (double)(RQDEPTH * NN);
      s += p * log(p);
    }
  }
  sh[threadIdx.x] = s;
  __syncthreads();
  for (int st = 128; st; st >>= 1) {
    if (threadIdx.x < st) sh[threadIdx.x] += sh[threadIdx.x + st];
    __syncthreads();
  }
  if (threadIdx.x == 0) out[0] = (float)exp(-sh[0]);
}

extern "C" void kernel_launch(void* const* d_in, const int* in_sizes, int n_in,
                              void* d_out, int out_size, void* d_ws, size_t ws_size,
                              hipStream_t stream) {
  const float* z  = (const float*)d_in[0];
  const float* cb = (const float*)d_in[1];
  float* out = (float*)d_out;
  const size_t PLANE = (size_t)NN * CC;          // 8,388,608
  float* cum  = out;                             // [4][B][C][H][W]
  float* zst  = out + (size_t)RQDEPTH * PLANE;   // [B][C][H][W]
  float* idxo = zst + PLANE;                     // [4][N]
  float* perp = idxo + (size_t)RQDEPTH * NN;     // scalar

  float* resid = (float*)d_ws;                   // N*C
  float* cbT   = resid + PLANE;                  // C*K
  float* Arow  = cbT + (size_t)CC * KK;          // N
  float* Bcol  = Arow + NN;                      // K
  int* idxAll  = (int*)(Bcol + KK);              // D*N
  int* counts  = idxAll + RQDEPTH * NN;          // K

  dim3 tgrid(HWt / 32, CC / 32, BB);             // 32 x 8 x 32
  k_ztrans<<<tgrid, 256, 0, stream>>>(z, resid);
  dim3 cgrid(KK / 32, CC / 32);
  k_cbtrans<<<cgrid, 256, 0, stream>>>(cb, cbT);
  k_bnorm<<<KK / 256, 256, 0, stream>>>(cb, Bcol);
  k_zero<<<(KK + 255) / 256, 256, 0, stream>>>(counts);

  for (int d = 0; d < RQDEPTH; ++d) {
    k_anorm<<<NN / 256, 256, 0, stream>>>(resid, Arow);
    k_bulk<<<NN / 16, 256, 0, stream>>>(resid, cbT, Arow, Bcol, idxAll,
                                        idxo + (size_t)d * NN, counts, d);
    k_update<<<tgrid, 256, 0, stream>>>(cb, idxAll, resid, cum, zst, d);
  }
  k_perp<<<1, 256, 0, stream>>>(counts, perp);
}